// Round 4
// baseline (83.256 us; speedup 1.0000x reference)
//
#include <hip/hip_runtime.h>
#include <hip/hip_bf16.h>

// RisingTideAttentionV2: out[m,:] = norm( exp(-||x_m - p_n|| / efft_n) ) @ V
// M=16384, N=4096, D=128. d2 = x2[m] + p2[n] - 2*dot(x_m,p_n). NEURON_SCALE=0.05125
//
// Barrier-free structure: block = 256 m-rows x 128 n-cols; each wave owns 32
// n-cols with P fragments loop-invariant in registers; X A-fragments are
// loaded directly from global bf16 (L1-shared across the 4 waves). Weights all
// underflow to exact 0.0f for this data; a skipped tile contributes exactly 0
// to numerator AND denominator, so the common path has no LDS, no barriers,
// and no reductions. The exact nonzero path (per-wave: f32 rsum reduce +
// atomicAdd, W redistribute via wave-private LDS, PV MFMA + atomicAdd into
// pre-zeroed d_out) is kept for full generality.

typedef __attribute__((ext_vector_type(8))) short short8;
typedef __attribute__((ext_vector_type(4))) float f32x4;

#define MTOT 16384
#define NTOT 4096
#define DD   128

__device__ __forceinline__ short f2bf(float f) {
    unsigned u = __float_as_uint(f);
    unsigned r = (u + 0x7fffu + ((u >> 16) & 1u)) >> 16;
    return (short)r;
}

// ---------------- prep ----------------
// blocks 0..511:    X -> bf16 Xb + x2g (32 rows each)
// blocks 512..639:  pos/val/temp -> Pb, p2g, cg, Vt (32 n each)
// blocks 640..1151: zero d_out (16 KB each)
// blocks 1152..1155: zero rsum_g (16 KB each)
__global__ __launch_bounds__(256) void tide_prep(
    const float* __restrict__ x, const float* __restrict__ pos,
    const float* __restrict__ val, const float* __restrict__ temp,
    short* __restrict__ Xb, float* __restrict__ x2g,
    short* __restrict__ Pb, float* __restrict__ p2g, float* __restrict__ cg,
    short* __restrict__ Vt, float* __restrict__ outz, float* __restrict__ rsz)
{
    const int bid = blockIdx.x, tid = threadIdx.x;
    if (bid < 512) {
        const int r = tid >> 3, sub = tid & 7;
        const int row = bid * 32 + r;
        const float* src = x + (size_t)row * DD + sub * 16;
        f32x4 a0 = ((const f32x4*)src)[0];
        f32x4 a1 = ((const f32x4*)src)[1];
        f32x4 a2 = ((const f32x4*)src)[2];
        f32x4 a3 = ((const f32x4*)src)[3];
        short8 h0, h1;
        h0[0]=f2bf(a0[0]); h0[1]=f2bf(a0[1]); h0[2]=f2bf(a0[2]); h0[3]=f2bf(a0[3]);
        h0[4]=f2bf(a1[0]); h0[5]=f2bf(a1[1]); h0[6]=f2bf(a1[2]); h0[7]=f2bf(a1[3]);
        h1[0]=f2bf(a2[0]); h1[1]=f2bf(a2[1]); h1[2]=f2bf(a2[2]); h1[3]=f2bf(a2[3]);
        h1[4]=f2bf(a3[0]); h1[5]=f2bf(a3[1]); h1[6]=f2bf(a3[2]); h1[7]=f2bf(a3[3]);
        *(short8*)(Xb + (size_t)row * DD + sub * 16)     = h0;
        *(short8*)(Xb + (size_t)row * DD + sub * 16 + 8) = h1;
        float s = a0[0]*a0[0]+a0[1]*a0[1]+a0[2]*a0[2]+a0[3]*a0[3]
                + a1[0]*a1[0]+a1[1]*a1[1]+a1[2]*a1[2]+a1[3]*a1[3]
                + a2[0]*a2[0]+a2[1]*a2[1]+a2[2]*a2[2]+a2[3]*a2[3]
                + a3[0]*a3[0]+a3[1]*a3[1]+a3[2]*a3[2]+a3[3]*a3[3];
        s += __shfl_xor(s, 1); s += __shfl_xor(s, 2); s += __shfl_xor(s, 4);
        if (sub == 0) x2g[row] = s;
    } else if (bid < 640) {
        __shared__ short ldsv[32][132];
        const int r = tid >> 3, sub = tid & 7;
        const int n0 = (bid - 512) * 32;
        const int n = n0 + r;
        const float* ps = pos + (size_t)n * DD + sub * 16;
        f32x4 a0 = ((const f32x4*)ps)[0];
        f32x4 a1 = ((const f32x4*)ps)[1];
        f32x4 a2 = ((const f32x4*)ps)[2];
        f32x4 a3 = ((const f32x4*)ps)[3];
        short8 h0, h1;
        h0[0]=f2bf(a0[0]); h0[1]=f2bf(a0[1]); h0[2]=f2bf(a0[2]); h0[3]=f2bf(a0[3]);
        h0[4]=f2bf(a1[0]); h0[5]=f2bf(a1[1]); h0[6]=f2bf(a1[2]); h0[7]=f2bf(a1[3]);
        h1[0]=f2bf(a2[0]); h1[1]=f2bf(a2[1]); h1[2]=f2bf(a2[2]); h1[3]=f2bf(a2[3]);
        h1[4]=f2bf(a3[0]); h1[5]=f2bf(a3[1]); h1[6]=f2bf(a3[2]); h1[7]=f2bf(a3[3]);
        *(short8*)(Pb + (size_t)n * DD + sub * 16)     = h0;
        *(short8*)(Pb + (size_t)n * DD + sub * 16 + 8) = h1;
        float s = a0[0]*a0[0]+a0[1]*a0[1]+a0[2]*a0[2]+a0[3]*a0[3]
                + a1[0]*a1[0]+a1[1]*a1[1]+a1[2]*a1[2]+a1[3]*a1[3]
                + a2[0]*a2[0]+a2[1]*a2[1]+a2[2]*a2[2]+a2[3]*a2[3]
                + a3[0]*a3[0]+a3[1]*a3[1]+a3[2]*a3[2]+a3[3]*a3[3];
        s += __shfl_xor(s, 1); s += __shfl_xor(s, 2); s += __shfl_xor(s, 4);
        if (sub == 0) {
            p2g[n] = s;
            float efft = (fabsf(temp[n]) + 0.1f) * 0.05125f;
            cg[n] = -1.4426950408889634f / efft;  // exp(-d/efft)=exp2(d*cg)
        }
        const float* vs = val + (size_t)n * DD + sub * 16;
        f32x4 b0 = ((const f32x4*)vs)[0];
        f32x4 b1 = ((const f32x4*)vs)[1];
        f32x4 b2 = ((const f32x4*)vs)[2];
        f32x4 b3 = ((const f32x4*)vs)[3];
        short* dstv = &ldsv[r][sub * 16];
        dstv[0]=f2bf(b0[0]); dstv[1]=f2bf(b0[1]); dstv[2]=f2bf(b0[2]); dstv[3]=f2bf(b0[3]);
        dstv[4]=f2bf(b1[0]); dstv[5]=f2bf(b1[1]); dstv[6]=f2bf(b1[2]); dstv[7]=f2bf(b1[3]);
        dstv[8]=f2bf(b2[0]); dstv[9]=f2bf(b2[1]); dstv[10]=f2bf(b2[2]); dstv[11]=f2bf(b2[3]);
        dstv[12]=f2bf(b3[0]); dstv[13]=f2bf(b3[1]); dstv[14]=f2bf(b3[2]); dstv[15]=f2bf(b3[3]);
        __syncthreads();
        const int d = tid >> 1, half = tid & 1;
        short8 t0, t1;
        #pragma unroll
        for (int j = 0; j < 8; ++j) t0[j] = ldsv[half * 16 + j][d];
        #pragma unroll
        for (int j = 0; j < 8; ++j) t1[j] = ldsv[half * 16 + 8 + j][d];
        *(short8*)(Vt + (size_t)d * NTOT + n0 + half * 16)     = t0;
        *(short8*)(Vt + (size_t)d * NTOT + n0 + half * 16 + 8) = t1;
    } else if (bid < 1152) {
        f32x4 z = {0.f, 0.f, 0.f, 0.f};
        float* dst = outz + (size_t)(bid - 640) * 4096;
        #pragma unroll
        for (int j = 0; j < 4; ++j)
            *(f32x4*)(dst + (size_t)(tid + 256 * j) * 4) = z;
    } else {
        f32x4 z = {0.f, 0.f, 0.f, 0.f};
        float* dst = rsz + (size_t)(bid - 1152) * 4096;
        #pragma unroll
        for (int j = 0; j < 4; ++j)
            *(f32x4*)(dst + (size_t)(tid + 256 * j) * 4) = z;
    }
}

// ---------------- main: barrier-free ----------------
// grid = 2048: blockIdx = mc*32 + nb. Block: rows mc*256..+255, cols nb*128..+127.
// Wave w: cols nb*128 + w*32 .. +31. 16 iters of 16 rows.
__global__ __launch_bounds__(256, 4) void tide_main(
    const short* __restrict__ Xb, const float* __restrict__ x2g,
    const short* __restrict__ Pb, const float* __restrict__ p2g,
    const float* __restrict__ cg, const short* __restrict__ Vt,
    float* __restrict__ rsum_g, float* __restrict__ oaccum)
{
    __shared__ __attribute__((aligned(16))) short lds_w[4][16 * 32];  // rare path only

    const int tid = threadIdx.x;
    const int wid = tid >> 6, lane = tid & 63;
    const int lo = lane & 15, hi = lane >> 4;
    const int nb = blockIdx.x & 31, mc = blockIdx.x >> 5;
    const int mb = mc * 256;
    const int ns0 = nb * 128 + wid * 32;

    // ---- loop-invariant P fragments: lane holds P[n=base+lo][k=(kf*4+hi)*8+j]
    short8 pf0[4], pf1[4];
    #pragma unroll
    for (int kf = 0; kf < 4; ++kf) {
        pf0[kf] = *(const short8*)(Pb + (size_t)(ns0 + lo) * DD + (kf * 4 + hi) * 8);
        pf1[kf] = *(const short8*)(Pb + (size_t)(ns0 + 16 + lo) * DD + (kf * 4 + hi) * 8);
    }
    const float p2v0 = p2g[ns0 + lo], p2v1 = p2g[ns0 + 16 + lo];
    const float cv0  = cg[ns0 + lo],  cv1  = cg[ns0 + 16 + lo];

    // ---- 1-deep software pipeline on the X fragment loads ----
    const short* xrow = Xb + (size_t)mb * DD + lo * DD;   // this lane's row base
    short8 xf[4];
    #pragma unroll
    for (int kf = 0; kf < 4; ++kf)
        xf[kf] = *(const short8*)(xrow + (kf * 4 + hi) * 8);

    for (int t = 0; t < 16; ++t) {
        const int m0 = mb + t * 16;
        f32x4 x2r = *(const f32x4*)(x2g + m0 + hi * 4);

        short8 xn[4];
        if (t < 15) {
            const short* xnext = xrow + (size_t)(t + 1) * 16 * DD;
            #pragma unroll
            for (int kf = 0; kf < 4; ++kf)
                xn[kf] = *(const short8*)(xnext + (kf * 4 + hi) * 8);
        }

        f32x4 s0 = {0.f,0.f,0.f,0.f}, s1 = {0.f,0.f,0.f,0.f};
        #pragma unroll
        for (int kf = 0; kf < 4; ++kf) {
            s0 = __builtin_amdgcn_mfma_f32_16x16x32_bf16(xf[kf], pf0[kf], s0, 0, 0, 0);
            s1 = __builtin_amdgcn_mfma_f32_16x16x32_bf16(xf[kf], pf1[kf], s1, 0, 0, 0);
        }

        // pointwise: C row m = m0 + hi*4 + r, cols ns0+lo / ns0+16+lo
        float w[8];
        float wmax = 0.f;
        #pragma unroll
        for (int r = 0; r < 4; ++r) {
            float d2a = fmaf(s0[r], -2.f, x2r[r] + p2v0);
            float d2b = fmaf(s1[r], -2.f, x2r[r] + p2v1);
            d2a = fmaxf(d2a, 0.f); d2b = fmaxf(d2b, 0.f);
            float wa = exp2f(__builtin_amdgcn_sqrtf(d2a) * cv0);
            float wb = exp2f(__builtin_amdgcn_sqrtf(d2b) * cv1);
            w[r] = wa; w[4 + r] = wb;
            wmax = fmaxf(wmax, fmaxf(wa, wb));
        }

        if (__builtin_expect(__any(wmax > 0.f), 0)) {
            // ---- exact rare path (per-wave, no cross-wave sync) ----
            #pragma unroll
            for (int r = 0; r < 4; ++r) {
                float v = w[r] + w[4 + r];
                v += __shfl_xor(v, 1); v += __shfl_xor(v, 2);
                v += __shfl_xor(v, 4); v += __shfl_xor(v, 8);
                if (lo == 0) atomicAdd(&rsum_g[m0 + hi * 4 + r], v);
            }
            // W -> wave-private LDS (C-layout in, A-layout out)
            #pragma unroll
            for (int r = 0; r < 4; ++r) {
                lds_w[wid][(hi * 4 + r) * 32 + lo]      = f2bf(w[r]);
                lds_w[wid][(hi * 4 + r) * 32 + 16 + lo] = f2bf(w[4 + r]);
            }
            short8 wfr = *(const short8*)(&lds_w[wid][lo * 32 + hi * 8]);
            #pragma unroll
            for (int df = 0; df < 8; ++df) {
                short8 vf = *(const short8*)(Vt + (size_t)(df * 16 + lo) * NTOT + ns0 + hi * 8);
                f32x4 of = {0.f,0.f,0.f,0.f};
                of = __builtin_amdgcn_mfma_f32_16x16x32_bf16(wfr, vf, of, 0, 0, 0);
                #pragma unroll
                for (int r = 0; r < 4; ++r)
                    atomicAdd(&oaccum[(size_t)(m0 + hi * 4 + r) * DD + df * 16 + lo], of[r]);
            }
        }

        #pragma unroll
        for (int kf = 0; kf < 4; ++kf) xf[kf] = xn[kf];
    }
}

// ---------------- normalize: only rows with nonzero rsum need work ----------
__global__ __launch_bounds__(256) void tide_norm(
    const float* __restrict__ rsum_g, float* __restrict__ outp)
{
    const int row = blockIdx.x * 256 + threadIdx.x;
    float s = rsum_g[row];
    if (s != 0.f) {   // rare: scale the row
        float inv = 1.f / (s + 1e-8f);
        float* p = outp + (size_t)row * DD;
        #pragma unroll 4
        for (int j = 0; j < DD / 4; ++j) {
            f32x4 v = *(f32x4*)(p + j * 4);
            v[0] *= inv; v[1] *= inv; v[2] *= inv; v[3] *= inv;
            *(f32x4*)(p + j * 4) = v;
        }
    }
    // s == 0: out row already exact (0 / (0 + 1e-8) = 0, pre-zeroed)
}

extern "C" void kernel_launch(void* const* d_in, const int* in_sizes, int n_in,
                              void* d_out, int out_size, void* d_ws, size_t ws_size,
                              hipStream_t stream) {
    const float* x    = (const float*)d_in[0];  // [8,2048,128]
    const float* pos  = (const float*)d_in[1];  // [4096,128]
    const float* val  = (const float*)d_in[2];  // [4096,128]
    const float* temp = (const float*)d_in[3];  // [4096]
    float* out = (float*)d_out;

    char* ws = (char*)d_ws;
    short* Xb     = (short*)(ws);                    // 4 MB
    short* Pb     = (short*)(ws + 4194304);          // 1 MB
    short* Vt     = (short*)(ws + 5242880);          // 1 MB
    float* x2g    = (float*)(ws + 6291456);          // 64 KB
    float* p2g    = (float*)(ws + 6356992);          // 16 KB
    float* cg     = (float*)(ws + 6373376);          // 16 KB
    float* rsum_g = (float*)(ws + 6389760);          // 64 KB

    hipLaunchKernelGGL(tide_prep, dim3(1156), dim3(256), 0, stream,
                       x, pos, val, temp, Xb, x2g, Pb, p2g, cg, Vt, out, rsum_g);
    hipLaunchKernelGGL(tide_main, dim3(2048), dim3(256), 0, stream,
                       Xb, x2g, Pb, p2g, cg, Vt, rsum_g, out);
    hipLaunchKernelGGL(tide_norm, dim3(64), dim3(256), 0, stream,
                       rsum_g, out);
}